// Round 4
// baseline (270.401 us; speedup 1.0000x reference)
//
#include <hip/hip_runtime.h>
#include <math.h>

#define VV 32000
#define TT 128
#define EE 64
#define NN 1024
#define NPART 500   // one partial per block per topic (each topic handled by 1 wave/block)

static constexpr float BOUND    = 1.41421356237309515f;   // sqrt(2)
static constexpr float LOG_SMIN = -2.30258509299404568f;  // log(0.1)
static constexpr float LOG_SMAX =  2.30258509299404568f;  // log(10)
static constexpr float LN2      =  0.69314718055994531f;
static constexpr float E_LOG2PI =  64.0f * 1.83787706640934548f; // E*log(2*pi)

typedef __attribute__((ext_vector_type(2)))  float f32x2;    // -> v_pk_*_f32
typedef __attribute__((ext_vector_type(8)))  short short8;   // 8 bf16 = 4 VGPRs
typedef __attribute__((ext_vector_type(16))) float float16;  // MFMA 32x32 acc

static __device__ inline unsigned short f2bf(float f) {
    union { float f; unsigned u; } v; v.f = f;
    unsigned r = v.u + 0x7FFFu + ((v.u >> 16) & 1u);  // round-to-nearest-even
    return (unsigned short)(r >> 16);
}

// ---------------- kernel 1: logits [T][V] + per-wave online softmax partials ----------------
// Block = 256 thr = 4 waves; owns 64 consecutive v (one per lane). prep_ctx fused:
// every block clamps+exps mu_c/log_sigma_c into its LDS. Inner loop in packed f32.
// Topic t is handled by wave (t&3) -> exactly one partial per (t, block): slot blockIdx.x.
__global__ __launch_bounds__(256) void logits_kernel(const float* __restrict__ mu,
                                                     const float* __restrict__ log_sigma,
                                                     const float* __restrict__ mu_c,
                                                     const float* __restrict__ log_sigma_c,
                                                     float* __restrict__ logitsT,
                                                     float* __restrict__ pm,
                                                     float* __restrict__ pl) {
    __shared__ float smem[16384];  // 64 KB: staging overlay then sc/mc
    float (*stage_s)[65] = (float(*)[65])smem;          // 64x65
    float (*stage_m)[65] = (float(*)[65])(smem + 4160); // 64x65
    const int tid = threadIdx.x;
    const int v0 = blockIdx.x * 64;

    // coalesced load of the 64x64 v-tile, transposed into LDS
    for (int k = tid; k < 64 * EE; k += 256) {
        int vi = k >> 6, e = k & 63;   // lanes -> consecutive e: coalesced global
        float ls = log_sigma[(v0 + vi) * EE + e];
        ls = fminf(fmaxf(ls, LOG_SMIN), LOG_SMAX);
        stage_s[e][vi] = __expf(ls);
        float m = mu[(v0 + vi) * EE + e];
        stage_m[e][vi] = fminf(fmaxf(m, -BOUND), BOUND);
    }
    __syncthreads();

    const int lane = tid & 63;
    const int wv   = tid >> 6;

    f32x2 sv[EE / 2], mv[EE / 2];
#pragma unroll
    for (int e = 0; e < EE / 2; e++) {
        sv[e] = f32x2{stage_s[2 * e][lane], stage_s[2 * e + 1][lane]};
        mv[e] = f32x2{stage_m[2 * e][lane], stage_m[2 * e + 1][lane]};
    }
    __syncthreads();  // staging reads done; safe to overlay

    // overlay: clamped/exp'd context params for all 128 topics (prep fused)
    float* scl = smem;          // 8192 floats
    float* mcl = smem + 8192;   // 8192 floats
    for (int i = tid; i < TT * EE; i += 256) {
        float ls = log_sigma_c[i];
        ls = fminf(fmaxf(ls, LOG_SMIN), LOG_SMAX);
        scl[i] = __expf(ls);
        float m = mu_c[i];
        mcl[i] = fminf(fmaxf(m, -BOUND), BOUND);
    }
    __syncthreads();

    for (int t = wv; t < TT; t += 4) {
        const f32x2* __restrict__ srow = (const f32x2*)(scl + t * EE);  // uniform: broadcast
        const f32x2* __restrict__ mrow = (const f32x2*)(mcl + t * EE);
        float acc_l2 = 0.0f;
        f32x2 q = {0.0f, 0.0f};
#pragma unroll
        for (int g = 0; g < 4; g++) {      // groups of 16 elems: product stays finite
            f32x2 p = {1.0f, 1.0f};
#pragma unroll
            for (int h = 0; h < 8; h++) {
                int e2 = g * 8 + h;
                f32x2 s = sv[e2] + srow[e2];   // v_pk_add_f32
                p *= s;                         // v_pk_mul_f32
                f32x2 d = mv[e2] - mrow[e2];
                f32x2 r;
                r.x = __builtin_amdgcn_rcpf(s.x);
                r.y = __builtin_amdgcn_rcpf(s.y);
                q += d * d * r;                 // v_pk_mul + v_pk_fma
            }
            acc_l2 += __log2f(p.x * p.y);       // s in [0.2,20]: 20^16 < 1e21, no overflow
        }
        float logit = -0.5f * (acc_l2 * LN2 + (q.x + q.y) + E_LOG2PI);
        logitsT[t * VV + v0 + lane] = logit;

        // per-wave online softmax partial (64 v's); one slot per (t, block)
        float m = logit;
#pragma unroll
        for (int off = 1; off < 64; off <<= 1) m = fmaxf(m, __shfl_xor(m, off));
        float s = __expf(logit - m);
#pragma unroll
        for (int off = 1; off < 64; off <<= 1) s += __shfl_xor(s, off);
        if (lane == 0) {
            int j = t * NPART + blockIdx.x;
            pm[j] = m;
            pl[j] = s;
        }
    }
}

// ---------------- kernel 2: merge partials (blocks 0..127) + x transpose (blocks 128..135) ----------------
__global__ __launch_bounds__(256) void merge_xpose(const float* __restrict__ pm,
                                                   const float* __restrict__ pl,
                                                   const float* __restrict__ x,
                                                   float* __restrict__ stats,
                                                   unsigned short* __restrict__ xT) {
    const int tid = threadIdx.x;
    __shared__ float red[8];
    if (blockIdx.x < TT) {
        const int t = blockIdx.x;
        float m = -3.4e38f;
        for (int j = tid; j < NPART; j += 256) m = fmaxf(m, pm[t * NPART + j]);
#pragma unroll
        for (int off = 1; off < 64; off <<= 1) m = fmaxf(m, __shfl_xor(m, off));
        if ((tid & 63) == 0) red[tid >> 6] = m;
        __syncthreads();
        m = fmaxf(fmaxf(red[0], red[1]), fmaxf(red[2], red[3]));

        float l = 0.0f;
        for (int j = tid; j < NPART; j += 256)
            l += pl[t * NPART + j] * __expf(pm[t * NPART + j] - m);
#pragma unroll
        for (int off = 1; off < 64; off <<= 1) l += __shfl_xor(l, off);
        if ((tid & 63) == 0) red[4 + (tid >> 6)] = l;
        __syncthreads();
        if (tid == 0) {
            float tot = red[4] + red[5] + red[6] + red[7];
            stats[t] = m;
            stats[TT + t] = 1.0f / tot;
        }
    } else {
        // transpose x [T][N] -> xT [N][T] bf16
        const int b = blockIdx.x - TT;         // 0..7
        const int n = b * 128 + (tid & 127);
        const int th = tid >> 7;               // 0..1
        const float* __restrict__ xp = x + n;
#pragma unroll
        for (int i = 0; i < 64; i += 2) {
            int t = th * 64 + i;
            float x0 = xp[(size_t)t * NN];     // lanes -> consecutive n: coalesced
            float x1 = xp[(size_t)(t + 1) * NN];
            *(unsigned*)&xT[n * TT + t] = (unsigned)f2bf(x0) | ((unsigned)f2bf(x1) << 16);
        }
    }
}

// ---------------- kernel 3: w_bf16 [V][T] = softmax weights, bf16 ----------------
// Reads logitsT [T][V] coalesced, LDS-transposes, writes [V][T] coalesced.
__global__ __launch_bounds__(256) void make_w(const float* __restrict__ logitsT,
                                              const float* __restrict__ stats,
                                              unsigned short* __restrict__ w) {
    __shared__ __attribute__((aligned(16))) unsigned short wl[64][136];
    __shared__ float sl[256];
    const int tid = threadIdx.x;
    const int v0 = blockIdx.x * 64;

    sl[tid] = stats[tid];  // 128 m then 128 inv_l
    __syncthreads();

    {
        const int v = tid & 63;
        const int tg = tid >> 6;
        const float* __restrict__ lp = logitsT + v0 + v;
#pragma unroll
        for (int i = 0; i < 32; i += 2) {
            int t = tg * 32 + i;
            float lg0 = lp[(size_t)t * VV];       // lanes -> consecutive v: coalesced
            float lg1 = lp[(size_t)(t + 1) * VV];
            float w0 = __expf(lg0 - sl[t])     * sl[TT + t];
            float w1 = __expf(lg1 - sl[t + 1]) * sl[TT + t + 1];
            *(unsigned*)&wl[v][t] = (unsigned)f2bf(w0) | ((unsigned)f2bf(w1) << 16);
        }
    }
    __syncthreads();

    {   // copy out coalesced: thread owns 32 shorts (64 B) of a row = 4 uint4
        const int v = tid >> 2;
        const int seg = (tid & 3) * 32;
#pragma unroll
        for (int j = 0; j < 4; j++) {
            uint4 d = *(const uint4*)&wl[v][seg + j * 8];
            *(uint4*)&w[(size_t)(v0 + v) * TT + seg + j * 8] = d;
        }
    }
}

// ---------------- kernel 4: out[V,N] = w @ x  (bf16 MFMA, LDS-free, barrier-free) ----------------
// Block 64v x 128n; wave = 32v x 64n = two 32x32x(K=128) chains; fragments loaded
// directly from global as contiguous 16B (w [V][T], xT [N][T] both k-contiguous).
__global__ __launch_bounds__(256) void wx_mfma(const unsigned short* __restrict__ w,
                                               const unsigned short* __restrict__ xT,
                                               float* __restrict__ out) {
    const int tid = threadIdx.x;
    const int v0 = blockIdx.x * 64;
    const int n0 = blockIdx.y * 128;
    const int lane = tid & 63;
    const int wv   = tid >> 6;
    const int vh   = (wv & 1) * 32;
    const int nh   = (wv >> 1) * 64;
    const int r32  = lane & 31;
    const int koff = (lane >> 5) * 8;

    const unsigned short* __restrict__ ap  = w  + (size_t)(v0 + vh + r32) * TT + koff;
    const unsigned short* __restrict__ bp0 = xT + (size_t)(n0 + nh + r32) * TT + koff;
    const unsigned short* __restrict__ bp1 = bp0 + 32 * TT;

    float16 acc0 = {0,0,0,0,0,0,0,0,0,0,0,0,0,0,0,0};
    float16 acc1 = {0,0,0,0,0,0,0,0,0,0,0,0,0,0,0,0};
#pragma unroll
    for (int kb = 0; kb < 8; kb++) {
        short8 a  = *(const short8*)(ap  + kb * 16);
        short8 b0 = *(const short8*)(bp0 + kb * 16);
        short8 b1 = *(const short8*)(bp1 + kb * 16);
        acc0 = __builtin_amdgcn_mfma_f32_32x32x16_bf16(a, b0, acc0, 0, 0, 0);
        acc1 = __builtin_amdgcn_mfma_f32_32x32x16_bf16(a, b1, acc1, 0, 0, 0);
    }

    const int col = lane & 31;
    const int rbase = 4 * (lane >> 5);
#pragma unroll
    for (int r = 0; r < 16; r++) {
        int row = (r & 3) + 8 * (r >> 2) + rbase;  // measured C/D layout (32x32)
        float* dst = out + (size_t)(v0 + vh + row) * NN + n0 + nh + col;
        dst[0]  = acc0[r];
        dst[32] = acc1[r];
    }
}

extern "C" void kernel_launch(void* const* d_in, const int* in_sizes, int n_in,
                              void* d_out, int out_size, void* d_ws, size_t ws_size,
                              hipStream_t stream) {
    const float* x           = (const float*)d_in[0];  // [T,N]
    const float* mu          = (const float*)d_in[1];  // [V,E]
    const float* log_sigma   = (const float*)d_in[2];  // [V,E]
    const float* mu_c        = (const float*)d_in[3];  // [T,E]
    const float* log_sigma_c = (const float*)d_in[4];  // [T,E]
    float* out = (float*)d_out;

    // ws layout (floats): logitsT [T*V] | pm [T*NPART] | pl [T*NPART] | stats [2T]
    //                     | w_bf16 [V*T]/2 | xT [N*T]/2
    float* ws      = (float*)d_ws;
    float* logitsT = ws;
    float* pm      = logitsT + (size_t)TT * VV;
    float* pl      = pm + (size_t)TT * NPART;
    float* stats   = pl + (size_t)TT * NPART;
    unsigned short* w_bf16 = (unsigned short*)(stats + 2 * TT);
    unsigned short* xT     = w_bf16 + (size_t)VV * TT;

    logits_kernel<<<VV / 64, 256, 0, stream>>>(mu, log_sigma, mu_c, log_sigma_c,
                                               logitsT, pm, pl);
    merge_xpose<<<TT + NN / 128, 256, 0, stream>>>(pm, pl, x, stats, xT);
    make_w<<<VV / 64, 256, 0, stream>>>(logitsT, stats, w_bf16);
    wx_mfma<<<dim3(VV / 64, NN / 128), 256, 0, stream>>>(w_bf16, xT, out);
}

// Round 5
// 250.937 us; speedup vs baseline: 1.0776x; 1.0776x over previous
//
#include <hip/hip_runtime.h>
#include <math.h>

#define VV 32000
#define TT 128
#define EE 64
#define NN 1024
#define NPART 500   // one softmax partial per (topic, v-tile-block)

static constexpr float BOUND    = 1.41421356237309515f;   // sqrt(2)
static constexpr float LOG_SMIN = -2.30258509299404568f;  // log(0.1)
static constexpr float LOG_SMAX =  2.30258509299404568f;  // log(10)
static constexpr float LN2      =  0.69314718055994531f;
static constexpr float E_LOG2PI =  64.0f * 1.83787706640934548f; // E*log(2*pi)

typedef __attribute__((ext_vector_type(2)))  float f32x2;    // -> v_pk_*_f32
typedef __attribute__((ext_vector_type(8)))  short short8;   // 8 bf16 = 4 VGPRs
typedef __attribute__((ext_vector_type(16))) float float16;  // MFMA 32x32 acc

static __device__ inline unsigned short f2bf(float f) {
    union { float f; unsigned u; } v; v.f = f;
    unsigned r = v.u + 0x7FFFu + ((v.u >> 16) & 1u);  // round-to-nearest-even
    return (unsigned short)(r >> 16);
}

// ---------------- kernel 0: clamp+exp the [T,E] context params ----------------
__global__ __launch_bounds__(256) void prep_ctx(const float* __restrict__ mu_c,
                                                const float* __restrict__ log_sigma_c,
                                                float* __restrict__ sc,
                                                float* __restrict__ mc) {
    int i = blockIdx.x * 256 + threadIdx.x;
    if (i < TT * EE) {
        float ls = log_sigma_c[i];
        ls = fminf(fmaxf(ls, LOG_SMIN), LOG_SMAX);
        sc[i] = __expf(ls);
        float m = mu_c[i];
        mc[i] = fminf(fmaxf(m, -BOUND), BOUND);
    }
}

// ---------------- kernel 1: logits [T][V], E split across waves ----------------
// Grid (V/64, 2). Block = 4 waves; lane = v (64 v/block), wave wv owns e-slice
// [16*wv, 16*wv+16). Per-lane state: 32 floats (no AGPR spill). ctx rows read as
// wave-uniform scalar loads (readfirstlane-forced). Per 8-topic phase: each wave
// folds its slice into ONE float per (t,v), combined through 8 KB LDS.
__global__ __launch_bounds__(256) void logits_kernel(const float* __restrict__ mu,
                                                     const float* __restrict__ log_sigma,
                                                     const float* __restrict__ sc,
                                                     const float* __restrict__ mc,
                                                     float* __restrict__ logitsT,
                                                     float* __restrict__ pm,
                                                     float* __restrict__ pl) {
    __shared__ float part[8][4][64];  // [t-in-phase][wave][lane] : 8 KB
    const int tid  = threadIdx.x;
    const int lane = tid & 63;
    const int wv   = tid >> 6;
    const int v0   = blockIdx.x * 64;
    const int t0   = blockIdx.y * 64;
    const int e0   = wv * 16;
    const int e0u  = __builtin_amdgcn_readfirstlane(wv) * 16;  // provably uniform

    // per-lane slice of sigma_v / mu_v: v = v0+lane, e in [e0, e0+16)
    f32x2 sv[8], mv[8];
    {
        const float* __restrict__ lsp = log_sigma + (size_t)(v0 + lane) * EE + e0;
        const float* __restrict__ mup = mu        + (size_t)(v0 + lane) * EE + e0;
#pragma unroll
        for (int j = 0; j < 8; j++) {
            float a = lsp[2 * j], b = lsp[2 * j + 1];
            a = fminf(fmaxf(a, LOG_SMIN), LOG_SMAX);
            b = fminf(fmaxf(b, LOG_SMIN), LOG_SMAX);
            sv[j] = f32x2{__expf(a), __expf(b)};
            float c = mup[2 * j], d = mup[2 * j + 1];
            mv[j] = f32x2{fminf(fmaxf(c, -BOUND), BOUND), fminf(fmaxf(d, -BOUND), BOUND)};
        }
    }

    for (int tb = 0; tb < 8; tb++) {           // 8 phases x 8 topics = 64 topics/block
        f32x2 q[8], p[8];
#pragma unroll
        for (int i = 0; i < 8; i++) { q[i] = f32x2{0.f, 0.f}; p[i] = f32x2{1.f, 1.f}; }
#pragma unroll
        for (int i = 0; i < 8; i++) {
            const int t = t0 + tb * 8 + i;
            const f32x2* __restrict__ srow = (const f32x2*)(sc + t * EE + e0u);  // uniform -> s_load
            const f32x2* __restrict__ mrow = (const f32x2*)(mc + t * EE + e0u);
#pragma unroll
            for (int j = 0; j < 8; j++) {
                f32x2 s = sv[j] + srow[j];      // v_pk_add_f32
                p[i] *= s;                      // v_pk_mul_f32
                f32x2 d = mv[j] - mrow[j];
                f32x2 r;
                r.x = __builtin_amdgcn_rcpf(s.x);
                r.y = __builtin_amdgcn_rcpf(s.y);
                q[i] += d * d * r;
            }
        }
        // fold slice to one float per (t, v): sum over 16 e of (log s + d^2/s)
#pragma unroll
        for (int i = 0; i < 8; i++) {
            // 16 factors, s in [0.2,20]: product in [6.6e-12, 6.6e20] — fp32 safe
            float contrib = __log2f(p[i].x * p[i].y) * LN2 + q[i].x + q[i].y;
            part[i][wv][lane] = contrib;
        }
        __syncthreads();
        // finalize: wave wv owns topics {2wv, 2wv+1} of this phase
#pragma unroll
        for (int k = 0; k < 2; k++) {
            const int i = wv * 2 + k;
            const int t = t0 + tb * 8 + i;
            float sum = part[i][0][lane] + part[i][1][lane] + part[i][2][lane] + part[i][3][lane];
            float logit = -0.5f * (sum + E_LOG2PI);
            logitsT[t * VV + v0 + lane] = logit;

            float m = logit;
#pragma unroll
            for (int off = 1; off < 64; off <<= 1) m = fmaxf(m, __shfl_xor(m, off));
            float sx = __expf(logit - m);
#pragma unroll
            for (int off = 1; off < 64; off <<= 1) sx += __shfl_xor(sx, off);
            if (lane == 0) {
                pm[t * NPART + blockIdx.x] = m;
                pl[t * NPART + blockIdx.x] = sx;
            }
        }
        __syncthreads();  // part[] reused next phase
    }
}

// ---------------- kernel 2: merge partials (blocks 0..127) + x transpose (blocks 128..135) ----------------
__global__ __launch_bounds__(256) void merge_xpose(const float* __restrict__ pm,
                                                   const float* __restrict__ pl,
                                                   const float* __restrict__ x,
                                                   float* __restrict__ stats,
                                                   unsigned short* __restrict__ xT) {
    const int tid = threadIdx.x;
    __shared__ float red[8];
    if (blockIdx.x < TT) {
        const int t = blockIdx.x;
        float m = -3.4e38f;
        for (int j = tid; j < NPART; j += 256) m = fmaxf(m, pm[t * NPART + j]);
#pragma unroll
        for (int off = 1; off < 64; off <<= 1) m = fmaxf(m, __shfl_xor(m, off));
        if ((tid & 63) == 0) red[tid >> 6] = m;
        __syncthreads();
        m = fmaxf(fmaxf(red[0], red[1]), fmaxf(red[2], red[3]));

        float l = 0.0f;
        for (int j = tid; j < NPART; j += 256)
            l += pl[t * NPART + j] * __expf(pm[t * NPART + j] - m);
#pragma unroll
        for (int off = 1; off < 64; off <<= 1) l += __shfl_xor(l, off);
        if ((tid & 63) == 0) red[4 + (tid >> 6)] = l;
        __syncthreads();
        if (tid == 0) {
            float tot = red[4] + red[5] + red[6] + red[7];
            stats[t] = m;
            stats[TT + t] = 1.0f / tot;
        }
    } else {
        // transpose x [T][N] -> xT [N][T] bf16
        const int b = blockIdx.x - TT;         // 0..7
        const int n = b * 128 + (tid & 127);
        const int th = tid >> 7;               // 0..1
        const float* __restrict__ xp = x + n;
#pragma unroll
        for (int i = 0; i < 64; i += 2) {
            int t = th * 64 + i;
            float x0 = xp[(size_t)t * NN];     // lanes -> consecutive n: coalesced
            float x1 = xp[(size_t)(t + 1) * NN];
            *(unsigned*)&xT[n * TT + t] = (unsigned)f2bf(x0) | ((unsigned)f2bf(x1) << 16);
        }
    }
}

// ---------------- kernel 3: w_bf16 [V][T] = softmax weights, bf16 ----------------
__global__ __launch_bounds__(256) void make_w(const float* __restrict__ logitsT,
                                              const float* __restrict__ stats,
                                              unsigned short* __restrict__ w) {
    __shared__ __attribute__((aligned(16))) unsigned short wl[64][136];
    __shared__ float sl[256];
    const int tid = threadIdx.x;
    const int v0 = blockIdx.x * 64;

    sl[tid] = stats[tid];  // 128 m then 128 inv_l
    __syncthreads();

    {
        const int v = tid & 63;
        const int tg = tid >> 6;
        const float* __restrict__ lp = logitsT + v0 + v;
#pragma unroll
        for (int i = 0; i < 32; i += 2) {
            int t = tg * 32 + i;
            float lg0 = lp[(size_t)t * VV];       // lanes -> consecutive v: coalesced
            float lg1 = lp[(size_t)(t + 1) * VV];
            float w0 = __expf(lg0 - sl[t])     * sl[TT + t];
            float w1 = __expf(lg1 - sl[t + 1]) * sl[TT + t + 1];
            *(unsigned*)&wl[v][t] = (unsigned)f2bf(w0) | ((unsigned)f2bf(w1) << 16);
        }
    }
    __syncthreads();

    {   // copy out coalesced: thread owns 32 shorts (64 B) of a row = 4 uint4
        const int v = tid >> 2;
        const int seg = (tid & 3) * 32;
#pragma unroll
        for (int j = 0; j < 4; j++) {
            uint4 d = *(const uint4*)&wl[v][seg + j * 8];
            *(uint4*)&w[(size_t)(v0 + v) * TT + seg + j * 8] = d;
        }
    }
}

// ---------------- kernel 4: out[V,N] = w @ x  (bf16 MFMA, LDS-free, barrier-free) ----------------
__global__ __launch_bounds__(256) void wx_mfma(const unsigned short* __restrict__ w,
                                               const unsigned short* __restrict__ xT,
                                               float* __restrict__ out) {
    const int tid = threadIdx.x;
    const int v0 = blockIdx.x * 64;
    const int n0 = blockIdx.y * 128;
    const int lane = tid & 63;
    const int wv   = tid >> 6;
    const int vh   = (wv & 1) * 32;
    const int nh   = (wv >> 1) * 64;
    const int r32  = lane & 31;
    const int koff = (lane >> 5) * 8;

    const unsigned short* __restrict__ ap  = w  + (size_t)(v0 + vh + r32) * TT + koff;
    const unsigned short* __restrict__ bp0 = xT + (size_t)(n0 + nh + r32) * TT + koff;
    const unsigned short* __restrict__ bp1 = bp0 + 32 * TT;

    float16 acc0 = {0,0,0,0,0,0,0,0,0,0,0,0,0,0,0,0};
    float16 acc1 = {0,0,0,0,0,0,0,0,0,0,0,0,0,0,0,0};
#pragma unroll
    for (int kb = 0; kb < 8; kb++) {
        short8 a  = *(const short8*)(ap  + kb * 16);
        short8 b0 = *(const short8*)(bp0 + kb * 16);
        short8 b1 = *(const short8*)(bp1 + kb * 16);
        acc0 = __builtin_amdgcn_mfma_f32_32x32x16_bf16(a, b0, acc0, 0, 0, 0);
        acc1 = __builtin_amdgcn_mfma_f32_32x32x16_bf16(a, b1, acc1, 0, 0, 0);
    }

    const int col = lane & 31;
    const int rbase = 4 * (lane >> 5);
#pragma unroll
    for (int r = 0; r < 16; r++) {
        int row = (r & 3) + 8 * (r >> 2) + rbase;  // measured C/D layout (32x32)
        float* dst = out + (size_t)(v0 + vh + row) * NN + n0 + nh + col;
        dst[0]  = acc0[r];
        dst[32] = acc1[r];
    }
}

extern "C" void kernel_launch(void* const* d_in, const int* in_sizes, int n_in,
                              void* d_out, int out_size, void* d_ws, size_t ws_size,
                              hipStream_t stream) {
    const float* x           = (const float*)d_in[0];  // [T,N]
    const float* mu          = (const float*)d_in[1];  // [V,E]
    const float* log_sigma   = (const float*)d_in[2];  // [V,E]
    const float* mu_c        = (const float*)d_in[3];  // [T,E]
    const float* log_sigma_c = (const float*)d_in[4];  // [T,E]
    float* out = (float*)d_out;

    // ws layout (floats): logitsT [T*V] | pm [T*NPART] | pl [T*NPART] | stats [2T]
    //                     | sc [T*E] | mc [T*E] | w_bf16 [V*T]/2 | xT [N*T]/2
    float* ws      = (float*)d_ws;
    float* logitsT = ws;
    float* pm      = logitsT + (size_t)TT * VV;
    float* pl      = pm + (size_t)TT * NPART;
    float* stats   = pl + (size_t)TT * NPART;
    float* sc      = stats + 2 * TT;
    float* mc      = sc + TT * EE;
    unsigned short* w_bf16 = (unsigned short*)(mc + TT * EE);
    unsigned short* xT     = w_bf16 + (size_t)VV * TT;

    prep_ctx<<<(TT * EE + 255) / 256, 256, 0, stream>>>(mu_c, log_sigma_c, sc, mc);
    logits_kernel<<<dim3(VV / 64, 2), 256, 0, stream>>>(mu, log_sigma, sc, mc,
                                                        logitsT, pm, pl);
    merge_xpose<<<TT + NN / 128, 256, 0, stream>>>(pm, pl, x, stats, xT);
    make_w<<<VV / 64, 256, 0, stream>>>(logitsT, stats, w_bf16);
    wx_mfma<<<dim3(VV / 64, NN / 128), 256, 0, stream>>>(w_bf16, xT, out);
}

// Round 6
// 246.727 us; speedup vs baseline: 1.0960x; 1.0171x over previous
//
#include <hip/hip_runtime.h>
#include <math.h>

#define VV 32000
#define TT 128
#define EE 64
#define NN 1024
#define NPART 500   // one softmax partial per (topic, v-tile-block)

static constexpr float BOUND    = 1.41421356237309515f;   // sqrt(2)
static constexpr float LOG_SMIN = -2.30258509299404568f;  // log(0.1)
static constexpr float LOG_SMAX =  2.30258509299404568f;  // log(10)
static constexpr float LN2      =  0.69314718055994531f;
static constexpr float E_LOG2PI =  64.0f * 1.83787706640934548f; // E*log(2*pi)

typedef __attribute__((ext_vector_type(2)))  float f32x2;    // -> v_pk_*_f32
typedef __attribute__((ext_vector_type(8)))  short short8;   // 8 bf16 = 4 VGPRs
typedef __attribute__((ext_vector_type(16))) float float16;  // MFMA 32x32 acc

static __device__ inline unsigned short f2bf(float f) {
    union { float f; unsigned u; } v; v.f = f;
    unsigned r = v.u + 0x7FFFu + ((v.u >> 16) & 1u);  // round-to-nearest-even
    return (unsigned short)(r >> 16);
}

// ---------------- kernel 0: ctx clamp+exp (blocks 0..31) + x transpose (blocks 32..39) ----------------
__global__ __launch_bounds__(256) void prep_xpose(const float* __restrict__ mu_c,
                                                  const float* __restrict__ log_sigma_c,
                                                  const float* __restrict__ x,
                                                  float* __restrict__ sc,
                                                  float* __restrict__ mc,
                                                  unsigned short* __restrict__ xT) {
    const int tid = threadIdx.x;
    if (blockIdx.x < 32) {
        int i = blockIdx.x * 256 + tid;
        if (i < TT * EE) {
            float ls = log_sigma_c[i];
            ls = fminf(fmaxf(ls, LOG_SMIN), LOG_SMAX);
            sc[i] = __expf(ls);
            float m = mu_c[i];
            mc[i] = fminf(fmaxf(m, -BOUND), BOUND);
        }
    } else {
        // transpose x [T][N] -> xT [N][T] bf16
        const int b = blockIdx.x - 32;         // 0..7
        const int n = b * 128 + (tid & 127);
        const int th = tid >> 7;               // 0..1
        const float* __restrict__ xp = x + n;
#pragma unroll
        for (int i = 0; i < 64; i += 2) {
            int t = th * 64 + i;
            float x0 = xp[(size_t)t * NN];     // lanes -> consecutive n: coalesced
            float x1 = xp[(size_t)(t + 1) * NN];
            *(unsigned*)&xT[n * TT + t] = (unsigned)f2bf(x0) | ((unsigned)f2bf(x1) << 16);
        }
    }
}

// ---------------- kernel 1: logits [T][V], E split across waves ----------------
// Grid (V/64, 4). Block = 4 waves; lane = v (64 v/block), wave wv owns e-slice
// [16*wv, 16*wv+16); block covers 32 topics. Per-lane sigma/mu slice: 32 VGPRs.
// ctx slices are wave-uniform scalar loads, DOUBLE-BUFFERED one topic ahead so
// SMEM latency overlaps the 200-cycle per-topic VALU body. Per 16-topic phase,
// the four e-slices combine through a 16 KB LDS partial buffer.
__global__ __launch_bounds__(256) void logits_kernel(const float* __restrict__ mu,
                                                     const float* __restrict__ log_sigma,
                                                     const float* __restrict__ sc,
                                                     const float* __restrict__ mc,
                                                     float* __restrict__ logitsT,
                                                     float* __restrict__ pm,
                                                     float* __restrict__ pl) {
    __shared__ float part[16][4][64];  // [t-in-phase][wave][lane] : 16 KB
    const int tid  = threadIdx.x;
    const int lane = tid & 63;
    const int wv   = tid >> 6;
    const int v0   = blockIdx.x * 64;
    const int t0   = blockIdx.y * 32;
    const int e0u  = __builtin_amdgcn_readfirstlane(wv) * 16;  // provably uniform

    // per-lane slice of sigma_v / mu_v: v = v0+lane, e in [e0u, e0u+16)
    f32x2 sv[8], mv[8];
    {
        const float* __restrict__ lsp = log_sigma + (size_t)(v0 + lane) * EE + e0u;
        const float* __restrict__ mup = mu        + (size_t)(v0 + lane) * EE + e0u;
#pragma unroll
        for (int j = 0; j < 8; j++) {
            float a = lsp[2 * j], b = lsp[2 * j + 1];
            a = fminf(fmaxf(a, LOG_SMIN), LOG_SMAX);
            b = fminf(fmaxf(b, LOG_SMIN), LOG_SMAX);
            sv[j] = f32x2{__expf(a), __expf(b)};
            float c = mup[2 * j], d = mup[2 * j + 1];
            mv[j] = f32x2{fminf(fmaxf(c, -BOUND), BOUND), fminf(fmaxf(d, -BOUND), BOUND)};
        }
    }

    // double-buffered wave-uniform ctx slices (16 sc + 16 mc floats per topic)
    f32x2 cs[2][8], cm[2][8];
    {
        const f32x2* __restrict__ sp = (const f32x2*)(sc + t0 * EE + e0u);
        const f32x2* __restrict__ mp = (const f32x2*)(mc + t0 * EE + e0u);
#pragma unroll
        for (int j = 0; j < 8; j++) { cs[0][j] = sp[j]; cm[0][j] = mp[j]; }
    }

    for (int tb = 0; tb < 2; tb++) {           // 2 phases x 16 topics = 32 topics
#pragma unroll
        for (int i = 0; i < 16; i++) {
            const int ti  = tb * 16 + i;       // 0..31 within block
            const int cur = ti & 1;
            if (ti < 31) {                     // prefetch next topic's slice
                const int tn = t0 + ti + 1;
                const f32x2* __restrict__ sp = (const f32x2*)(sc + tn * EE + e0u);
                const f32x2* __restrict__ mp = (const f32x2*)(mc + tn * EE + e0u);
#pragma unroll
                for (int j = 0; j < 8; j++) { cs[cur ^ 1][j] = sp[j]; cm[cur ^ 1][j] = mp[j]; }
            }
            f32x2 q = {0.f, 0.f};
            f32x2 p = {1.f, 1.f};
#pragma unroll
            for (int j = 0; j < 8; j++) {
                f32x2 s = sv[j] + cs[cur][j];   // v_pk_add_f32
                p *= s;                          // v_pk_mul_f32
                f32x2 d = mv[j] - cm[cur][j];
                f32x2 r;
                r.x = __builtin_amdgcn_rcpf(s.x);
                r.y = __builtin_amdgcn_rcpf(s.y);
                q += d * d * r;
            }
            // 16 factors, s in [0.2,20]: product in [6.6e-12, 6.6e20] — fp32 safe
            part[i][wv][lane] = __log2f(p.x * p.y) * LN2 + q.x + q.y;
        }
        __syncthreads();
        // finalize: wave wv owns topics i = 4*wv..4*wv+3 of this phase
#pragma unroll
        for (int k = 0; k < 4; k++) {
            const int i = wv * 4 + k;
            const int t = t0 + tb * 16 + i;
            float sum = part[i][0][lane] + part[i][1][lane] + part[i][2][lane] + part[i][3][lane];
            float logit = -0.5f * (sum + E_LOG2PI);
            logitsT[t * VV + v0 + lane] = logit;

            float m = logit;
#pragma unroll
            for (int off = 1; off < 64; off <<= 1) m = fmaxf(m, __shfl_xor(m, off));
            float sx = __expf(logit - m);
#pragma unroll
            for (int off = 1; off < 64; off <<= 1) sx += __shfl_xor(sx, off);
            if (lane == 0) {
                pm[t * NPART + blockIdx.x] = m;
                pl[t * NPART + blockIdx.x] = sx;
            }
        }
        __syncthreads();  // part[] reused next phase
    }
}

// ---------------- kernel 2: merge softmax partials -> stats ----------------
__global__ __launch_bounds__(256) void merge_stats(const float* __restrict__ pm,
                                                   const float* __restrict__ pl,
                                                   float* __restrict__ stats) {
    const int tid = threadIdx.x;
    const int t = blockIdx.x;
    __shared__ float red[8];
    float m = -3.4e38f;
    for (int j = tid; j < NPART; j += 256) m = fmaxf(m, pm[t * NPART + j]);
#pragma unroll
    for (int off = 1; off < 64; off <<= 1) m = fmaxf(m, __shfl_xor(m, off));
    if ((tid & 63) == 0) red[tid >> 6] = m;
    __syncthreads();
    m = fmaxf(fmaxf(red[0], red[1]), fmaxf(red[2], red[3]));

    float l = 0.0f;
    for (int j = tid; j < NPART; j += 256)
        l += pl[t * NPART + j] * __expf(pm[t * NPART + j] - m);
#pragma unroll
    for (int off = 1; off < 64; off <<= 1) l += __shfl_xor(l, off);
    if ((tid & 63) == 0) red[4 + (tid >> 6)] = l;
    __syncthreads();
    if (tid == 0) {
        float tot = red[4] + red[5] + red[6] + red[7];
        stats[t] = m;
        stats[TT + t] = 1.0f / tot;
    }
}

// ---------------- kernel 3: w_bf16 [V][T] = softmax weights, bf16 ----------------
__global__ __launch_bounds__(256) void make_w(const float* __restrict__ logitsT,
                                              const float* __restrict__ stats,
                                              unsigned short* __restrict__ w) {
    __shared__ __attribute__((aligned(16))) unsigned short wl[64][136];
    __shared__ float sl[256];
    const int tid = threadIdx.x;
    const int v0 = blockIdx.x * 64;

    sl[tid] = stats[tid];  // 128 m then 128 inv_l
    __syncthreads();

    {
        const int v = tid & 63;
        const int tg = tid >> 6;
        const float* __restrict__ lp = logitsT + v0 + v;
#pragma unroll
        for (int i = 0; i < 32; i += 2) {
            int t = tg * 32 + i;
            float lg0 = lp[(size_t)t * VV];       // lanes -> consecutive v: coalesced
            float lg1 = lp[(size_t)(t + 1) * VV];
            float w0 = __expf(lg0 - sl[t])     * sl[TT + t];
            float w1 = __expf(lg1 - sl[t + 1]) * sl[TT + t + 1];
            *(unsigned*)&wl[v][t] = (unsigned)f2bf(w0) | ((unsigned)f2bf(w1) << 16);
        }
    }
    __syncthreads();

    {   // copy out coalesced: thread owns 32 shorts (64 B) of a row = 4 uint4
        const int v = tid >> 2;
        const int seg = (tid & 3) * 32;
#pragma unroll
        for (int j = 0; j < 4; j++) {
            uint4 d = *(const uint4*)&wl[v][seg + j * 8];
            *(uint4*)&w[(size_t)(v0 + v) * TT + seg + j * 8] = d;
        }
    }
}

// ---------------- kernel 4: out[V,N] = w @ x  (bf16 MFMA, LDS-free, barrier-free) ----------------
// Grid (N/128, V/64): the 8 n-blocks of one v-tile are dispatch-adjacent, so the
// 16 KB w-tile stays L2-resident across its 8 consumers (was L3-served before).
__global__ __launch_bounds__(256) void wx_mfma(const unsigned short* __restrict__ w,
                                               const unsigned short* __restrict__ xT,
                                               float* __restrict__ out) {
    const int tid = threadIdx.x;
    const int n0 = blockIdx.x * 128;
    const int v0 = blockIdx.y * 64;
    const int lane = tid & 63;
    const int wv   = tid >> 6;
    const int vh   = (wv & 1) * 32;
    const int nh   = (wv >> 1) * 64;
    const int r32  = lane & 31;
    const int koff = (lane >> 5) * 8;

    const unsigned short* __restrict__ ap  = w  + (size_t)(v0 + vh + r32) * TT + koff;
    const unsigned short* __restrict__ bp0 = xT + (size_t)(n0 + nh + r32) * TT + koff;
    const unsigned short* __restrict__ bp1 = bp0 + 32 * TT;

    float16 acc0 = {0,0,0,0,0,0,0,0,0,0,0,0,0,0,0,0};
    float16 acc1 = {0,0,0,0,0,0,0,0,0,0,0,0,0,0,0,0};
#pragma unroll
    for (int kb = 0; kb < 8; kb++) {
        short8 a  = *(const short8*)(ap  + kb * 16);
        short8 b0 = *(const short8*)(bp0 + kb * 16);
        short8 b1 = *(const short8*)(bp1 + kb * 16);
        acc0 = __builtin_amdgcn_mfma_f32_32x32x16_bf16(a, b0, acc0, 0, 0, 0);
        acc1 = __builtin_amdgcn_mfma_f32_32x32x16_bf16(a, b1, acc1, 0, 0, 0);
    }

    const int col = lane & 31;
    const int rbase = 4 * (lane >> 5);
#pragma unroll
    for (int r = 0; r < 16; r++) {
        int row = (r & 3) + 8 * (r >> 2) + rbase;  // measured C/D layout (32x32)
        float* dst = out + (size_t)(v0 + vh + row) * NN + n0 + nh + col;
        dst[0]  = acc0[r];
        dst[32] = acc1[r];
    }
}

extern "C" void kernel_launch(void* const* d_in, const int* in_sizes, int n_in,
                              void* d_out, int out_size, void* d_ws, size_t ws_size,
                              hipStream_t stream) {
    const float* x           = (const float*)d_in[0];  // [T,N]
    const float* mu          = (const float*)d_in[1];  // [V,E]
    const float* log_sigma   = (const float*)d_in[2];  // [V,E]
    const float* mu_c        = (const float*)d_in[3];  // [T,E]
    const float* log_sigma_c = (const float*)d_in[4];  // [T,E]
    float* out = (float*)d_out;

    // ws layout (floats): logitsT [T*V] | pm [T*NPART] | pl [T*NPART] | stats [2T]
    //                     | sc [T*E] | mc [T*E] | w_bf16 [V*T]/2 | xT [N*T]/2
    float* ws      = (float*)d_ws;
    float* logitsT = ws;
    float* pm      = logitsT + (size_t)TT * VV;
    float* pl      = pm + (size_t)TT * NPART;
    float* stats   = pl + (size_t)TT * NPART;
    float* sc      = stats + 2 * TT;
    float* mc      = sc + TT * EE;
    unsigned short* w_bf16 = (unsigned short*)(mc + TT * EE);
    unsigned short* xT     = w_bf16 + (size_t)VV * TT;

    prep_xpose<<<40, 256, 0, stream>>>(mu_c, log_sigma_c, x, sc, mc, xT);
    logits_kernel<<<dim3(VV / 64, 4), 256, 0, stream>>>(mu, log_sigma, sc, mc,
                                                        logitsT, pm, pl);
    merge_stats<<<TT, 256, 0, stream>>>(pm, pl, stats);
    make_w<<<VV / 64, 256, 0, stream>>>(logitsT, stats, w_bf16);
    wx_mfma<<<dim3(NN / 128, VV / 64), 256, 0, stream>>>(w_bf16, xT, out);
}